// Round 10
// baseline (20.991 us; speedup 1.0000x reference)
//
#include <hip/hip_runtime.h>

// Problem constants (match reference)
#define HH    128
#define WW    128
#define CDIM  4
#define DK    3
#define FDIM  4
#define DEPTH 16
#define DOUT  14
#define NB    4
#define HW    (HH * WW)          // 16384
#define TROWS 4                  // output rows per block
#define HROWS (TROWS + 2)        // halo rows of Q per block
#define NTILE (HH / TROWS)       // 32 h-tiles
#define NIG   4                  // i-groups: {0-3,4-7,8-11,12-13(partial)}

#define WCONV_BLOCKS 48                     // 48 * 256 * 16 = 196608 float4s

typedef float nfloat4 __attribute__((ext_vector_type(4)));  // native vec for nt-store

__device__ __forceinline__ float bf2f(unsigned short u) {
    return __uint_as_float(((unsigned int)u) << 16);
}
__device__ __forceinline__ unsigned short f2bf_rtne(float f) {
    unsigned int u = __float_as_uint(f);
    u += 0x7FFFu + ((u >> 16) & 1u);        // round-to-nearest-even
    return (unsigned short)(u >> 16);
}

// ---------------------------------------------------------------------------
// Kernel A (fused pre-pass):
//  blocks 0..63   : bsum[f,h,w] = sum_{c,dd} bias[f,0,c,dd,h,w]  (float4)
//  blocks 64..111 : weight f32 -> bf16 (RTN-even) repack
// ---------------------------------------------------------------------------
__global__ __launch_bounds__(256) void prepass_kernel(const float4* __restrict__ bias,
                                                      const float4* __restrict__ wgt,
                                                      float4* __restrict__ bsum,
                                                      ushort4* __restrict__ w16) {
    const int blk = blockIdx.x;
    const int tid = threadIdx.x;
    if (blk < 64) {
        int idx = blk * 256 + tid;                 // over f*H*W/4 = 16384
        int f   = idx >> 12;
        int hw4 = idx & 4095;
        const float4* bp = bias + f * (CDIM * DK * (HW / 4)) + hw4;
        float4 s = make_float4(0.f, 0.f, 0.f, 0.f);
#pragma unroll
        for (int c = 0; c < CDIM; ++c)
#pragma unroll
            for (int dd = 0; dd < DK; ++dd) {
                float4 v = bp[(c * DK + dd) * (HW / 4)];
                s.x += v.x; s.y += v.y; s.z += v.z; s.w += v.w;
            }
        bsum[idx] = s;
    } else {
        const int local = blk - 64;                // 0..47
#pragma unroll
        for (int k = 0; k < 16; ++k) {
            int idx = local * 4096 + k * 256 + tid;
            float4 v = wgt[idx];
            ushort4 o;
            o.x = f2bf_rtne(v.x); o.y = f2bf_rtne(v.y);
            o.z = f2bf_rtne(v.z); o.w = f2bf_rtne(v.w);
            w16[idx] = o;
        }
    }
}

// ---------------------------------------------------------------------------
// Kernel B: fused Q + 3x3 box-sum + leaky ReLU, 4 depth-outputs per block.
// R9 structure + XCD-aware block swizzle: each (b,ig) group (x-slice 1.5 MB +
// w16 1.5 MB + bsum 0.25 MB ~= 3.25 MB) is pinned to one XCD's 4 MB L2.
// Assumes hw round-robin dispatch (XCD = blockIdx % 8) — perf-only heuristic.
// ---------------------------------------------------------------------------
__global__ __launch_bounds__(256, 2) void linerconv_main(const float* __restrict__ x,
                                                         const unsigned short* __restrict__ w16,
                                                         const float* __restrict__ bsum,
                                                         float* __restrict__ out) {
    // ---- XCD swizzle: physical p -> (group, tile) with group pinned per XCD
    const int p    = blockIdx.x;          // 0..511
    const int xcd  = p & 7;
    const int s    = p >> 3;              // 0..63
    const int grp  = xcd + 8 * (s >> 5);  // 0..15  (2 groups per XCD, sequential)
    const int tile = s & 31;              // 0..31
    const int ig   = grp & 3;
    const int b    = grp >> 2;
    const int i0   = ig * 4;              // 0,4,8,12 (last group: 2 i only)
    const int h0   = tile * TROWS;
    const bool full = (ig != NIG - 1);

    __shared__ float lds[4][FDIM][HROWS][WW]; // 48 KB

    const int tid = threadIdx.x;

    // ---- Phase 1: 192 threads fill HROWS x WW of Q for nI i and 4 f ----
    if (tid < HROWS * 32) {
        const int row = tid >> 5;             // 0..5
        const int q   = tid & 31;
        const int g   = h0 - 1 + row;
        if (g >= 0 && g < HH) {
            const int base_hw = g * WW + q * 4;
            const float* xb = x + (b * CDIM * DEPTH + i0) * HW + base_hw;
            const unsigned short* wb = w16 + base_hw;
            if (full) {
                float4 acc[4][FDIM];
#pragma unroll
                for (int f = 0; f < FDIM; ++f) {
                    float4 bv = *(const float4*)(bsum + f * HW + base_hw);
#pragma unroll
                    for (int i2 = 0; i2 < 4; ++i2) acc[i2][f] = bv;
                }
#pragma unroll
                for (int c = 0; c < CDIM; ++c) {
                    float4 xp[6];                 // planes i0 .. i0+5
#pragma unroll
                    for (int j = 0; j < 6; ++j)
                        xp[j] = *(const float4*)(xb + c * (DEPTH * HW) + j * HW);
#pragma unroll
                    for (int dd = 0; dd < DK; ++dd) {
#pragma unroll
                        for (int f = 0; f < FDIM; ++f) {
                            ushort4 wu = *(const ushort4*)(wb + ((f * CDIM + c) * DK + dd) * HW);
                            float wx = bf2f(wu.x), wy = bf2f(wu.y);
                            float wz = bf2f(wu.z), ww = bf2f(wu.w);
#pragma unroll
                            for (int i2 = 0; i2 < 4; ++i2) {
                                acc[i2][f].x += xp[i2 + dd].x * wx;
                                acc[i2][f].y += xp[i2 + dd].y * wy;
                                acc[i2][f].z += xp[i2 + dd].z * wz;
                                acc[i2][f].w += xp[i2 + dd].w * ww;
                            }
                        }
                    }
                }
#pragma unroll
                for (int i2 = 0; i2 < 4; ++i2)
#pragma unroll
                    for (int f = 0; f < FDIM; ++f)
                        *(float4*)&lds[i2][f][row][q * 4] = acc[i2][f];
            } else {
                // partial group: i = 12,13 -> planes 12..15 only
                float4 acc[2][FDIM];
#pragma unroll
                for (int f = 0; f < FDIM; ++f) {
                    float4 bv = *(const float4*)(bsum + f * HW + base_hw);
                    acc[0][f] = bv;
                    acc[1][f] = bv;
                }
#pragma unroll
                for (int c = 0; c < CDIM; ++c) {
                    float4 xp[4];
#pragma unroll
                    for (int j = 0; j < 4; ++j)
                        xp[j] = *(const float4*)(xb + c * (DEPTH * HW) + j * HW);
#pragma unroll
                    for (int dd = 0; dd < DK; ++dd) {
#pragma unroll
                        for (int f = 0; f < FDIM; ++f) {
                            ushort4 wu = *(const ushort4*)(wb + ((f * CDIM + c) * DK + dd) * HW);
                            float wx = bf2f(wu.x), wy = bf2f(wu.y);
                            float wz = bf2f(wu.z), ww = bf2f(wu.w);
#pragma unroll
                            for (int i2 = 0; i2 < 2; ++i2) {
                                acc[i2][f].x += xp[i2 + dd].x * wx;
                                acc[i2][f].y += xp[i2 + dd].y * wy;
                                acc[i2][f].z += xp[i2 + dd].z * wz;
                                acc[i2][f].w += xp[i2 + dd].w * ww;
                            }
                        }
                    }
                }
#pragma unroll
                for (int i2 = 0; i2 < 2; ++i2)
#pragma unroll
                    for (int f = 0; f < FDIM; ++f)
                        *(float4*)&lds[i2][f][row][q * 4] = acc[i2][f];
            }
        } else {
            float4 z = make_float4(0.f, 0.f, 0.f, 0.f);
#pragma unroll
            for (int i2 = 0; i2 < 4; ++i2)
#pragma unroll
                for (int f = 0; f < FDIM; ++f)
                    *(float4*)&lds[i2][f][row][q * 4] = z;
        }
    }
    __syncthreads();

    // ---- Phase 2: vectorized column box sums + leaky, float4 nt-stores ----
    auto do_quadcol = [&](int idx) {
        const int q  = idx & 31;
        const int f  = (idx >> 5) & 3;
        const int i2 = idx >> 7;
        const float* Lb = &lds[i2][f][0][0];
        float4 rs[HROWS];
#pragma unroll
        for (int g = 0; g < HROWS; ++g) {
            const float* Lr = Lb + g * WW;
            float4 m  = *(const float4*)(Lr + q * 4);
            float lft = (q > 0)  ? Lr[q * 4 - 1] : 0.f;
            float rgt = (q < 31) ? Lr[q * 4 + 4] : 0.f;
            rs[g].x = lft + m.x + m.y;
            rs[g].y = m.x + m.y + m.z;
            rs[g].z = m.y + m.z + m.w;
            rs[g].w = m.z + m.w + rgt;
        }
        float* op = out + ((b * FDIM + f) * DOUT + (i0 + i2)) * HW + h0 * WW + q * 4;
#pragma unroll
        for (int r = 0; r < TROWS; ++r) {
            nfloat4 s;
            s.x = rs[r].x + rs[r + 1].x + rs[r + 2].x;
            s.y = rs[r].y + rs[r + 1].y + rs[r + 2].y;
            s.z = rs[r].z + rs[r + 1].z + rs[r + 2].z;
            s.w = rs[r].w + rs[r + 1].w + rs[r + 2].w;
            s.x = (s.x >= 0.f) ? s.x : 0.2f * s.x;
            s.y = (s.y >= 0.f) ? s.y : 0.2f * s.y;
            s.z = (s.z >= 0.f) ? s.z : 0.2f * s.z;
            s.w = (s.w >= 0.f) ? s.w : 0.2f * s.w;
            __builtin_nontemporal_store(s, (nfloat4*)(op + r * WW));
        }
    };
    do_quadcol(tid);
    if (full) do_quadcol(tid + 256);
}

extern "C" void kernel_launch(void* const* d_in, const int* in_sizes, int n_in,
                              void* d_out, int out_size, void* d_ws, size_t ws_size,
                              hipStream_t stream) {
    const float* x    = (const float*)d_in[0];   // [4,4,16,128,128]
    const float* wgt  = (const float*)d_in[1];   // [4,1,4,3,128,128]
    const float* bias = (const float*)d_in[2];   // [4,1,4,3,128,128]
    float* out  = (float*)d_out;                 // [4,4,14,128,128]

    float*          bsum = (float*)d_ws;                                // 256 KB
    unsigned short* w16  = (unsigned short*)((char*)d_ws + 65536 * 4);  // 1.5 MB

    prepass_kernel<<<64 + WCONV_BLOCKS, 256, 0, stream>>>(
        (const float4*)bias, (const float4*)wgt, (float4*)bsum, (ushort4*)w16);
    linerconv_main<<<NB * NIG * NTILE, 256, 0, stream>>>(x, w16, bsum, out);
}